// Round 1
// baseline (1041.644 us; speedup 1.0000x reference)
//
#include <hip/hip_runtime.h>
#include <hip/hip_bf16.h>

#define NROWS 65536
#define DDIM  2048
#define NEXP  8
#define ROWS_PER_BLOCK 32
#define THREADS 256

// Kernel A: per-row gate scores -> softmax over allowed half -> top1 + prob.
// Stores prob at out[row*8+0], top1 (as float) at out[row*8+1], and
// accumulates denom[top1] += prob via global atomics.
__global__ __launch_bounds__(THREADS, 2) void gate_kernel(
    const float* __restrict__ x,       // (B, D)
    const int*   __restrict__ label,   // (B,)
    const float* __restrict__ w,       // (D, E) row-major
    const float* __restrict__ bgate,   // (E,)
    float* __restrict__ out,           // (B, E) — temp storage slots 0,1
    float* __restrict__ denom)         // (E,) pre-zeroed
{
    __shared__ float wt[NEXP * DDIM];  // wt[e*D + d], exactly 64 KiB

    const int tid = threadIdx.x;

    // Stage w transposed into LDS: read (D,E) row-major as float4, scatter.
    for (int i = tid; i < (DDIM * NEXP) / 4; i += THREADS) {
        float4 v = reinterpret_cast<const float4*>(w)[i];
        int d0 = i >> 1;            // f0 = 4*i = d0*8 + e0
        int e0 = (i & 1) * 4;
        wt[(e0 + 0) * DDIM + d0] = v.x;
        wt[(e0 + 1) * DDIM + d0] = v.y;
        wt[(e0 + 2) * DDIM + d0] = v.z;
        wt[(e0 + 3) * DDIM + d0] = v.w;
    }
    float bg[NEXP];
#pragma unroll
    for (int e = 0; e < NEXP; ++e) bg[e] = bgate[e];
    __syncthreads();

    const int wave = tid >> 6;
    const int lane = tid & 63;
    const int row_base = blockIdx.x * ROWS_PER_BLOCK + wave * (ROWS_PER_BLOCK / 4);

    for (int p = 0; p < ROWS_PER_BLOCK / 8; ++p) {   // 4 pairs of rows per wave
        const int row0 = row_base + p * 2;
        const float* x0 = x + (size_t)row0 * DDIM;
        const float* x1 = x0 + DDIM;

        float acc0[NEXP], acc1[NEXP];
#pragma unroll
        for (int e = 0; e < NEXP; ++e) { acc0[e] = 0.f; acc1[e] = 0.f; }

#pragma unroll
        for (int k = 0; k < DDIM / 256; ++k) {
            const int d0 = k * 256 + lane * 4;
            float4 a = *reinterpret_cast<const float4*>(x0 + d0);
            float4 c = *reinterpret_cast<const float4*>(x1 + d0);
#pragma unroll
            for (int e = 0; e < NEXP; ++e) {
                float4 wv = *reinterpret_cast<const float4*>(&wt[e * DDIM + d0]);
                acc0[e] += a.x * wv.x + a.y * wv.y + a.z * wv.z + a.w * wv.w;
                acc1[e] += c.x * wv.x + c.y * wv.y + c.z * wv.z + c.w * wv.w;
            }
        }

        // Wave reduction: butterfly so every lane has all 16 sums.
#pragma unroll
        for (int e = 0; e < NEXP; ++e) {
#pragma unroll
            for (int m = 32; m >= 1; m >>= 1) {
                acc0[e] += __shfl_xor(acc0[e], m, 64);
                acc1[e] += __shfl_xor(acc1[e], m, 64);
            }
        }

        const int lab0 = label[row0];
        const int lab1 = label[row0 + 1];

        // Row 0 epilogue (all lanes compute; static indexing only)
        float s0[NEXP], s1[NEXP];
#pragma unroll
        for (int e = 0; e < NEXP; ++e) { s0[e] = acc0[e] + bg[e]; s1[e] = acc1[e] + bg[e]; }

        // ---- row 0: both halves, then select by label ----
        float mA0 = s0[0]; int aA0 = 0;
        if (s0[1] > mA0) { mA0 = s0[1]; aA0 = 1; }
        if (s0[2] > mA0) { mA0 = s0[2]; aA0 = 2; }
        if (s0[3] > mA0) { mA0 = s0[3]; aA0 = 3; }
        float sumA0 = expf(s0[0] - mA0) + expf(s0[1] - mA0) + expf(s0[2] - mA0) + expf(s0[3] - mA0);
        float mB0 = s0[4]; int aB0 = 4;
        if (s0[5] > mB0) { mB0 = s0[5]; aB0 = 5; }
        if (s0[6] > mB0) { mB0 = s0[6]; aB0 = 6; }
        if (s0[7] > mB0) { mB0 = s0[7]; aB0 = 7; }
        float sumB0 = expf(s0[4] - mB0) + expf(s0[5] - mB0) + expf(s0[6] - mB0) + expf(s0[7] - mB0);
        const int   arg0 = lab0 ? aB0 : aA0;
        const float pv0  = 1.0f / (lab0 ? sumB0 : sumA0);

        // ---- row 1 ----
        float mA1 = s1[0]; int aA1 = 0;
        if (s1[1] > mA1) { mA1 = s1[1]; aA1 = 1; }
        if (s1[2] > mA1) { mA1 = s1[2]; aA1 = 2; }
        if (s1[3] > mA1) { mA1 = s1[3]; aA1 = 3; }
        float sumA1 = expf(s1[0] - mA1) + expf(s1[1] - mA1) + expf(s1[2] - mA1) + expf(s1[3] - mA1);
        float mB1 = s1[4]; int aB1 = 4;
        if (s1[5] > mB1) { mB1 = s1[5]; aB1 = 5; }
        if (s1[6] > mB1) { mB1 = s1[6]; aB1 = 6; }
        if (s1[7] > mB1) { mB1 = s1[7]; aB1 = 7; }
        float sumB1 = expf(s1[4] - mB1) + expf(s1[5] - mB1) + expf(s1[6] - mB1) + expf(s1[7] - mB1);
        const int   arg1 = lab1 ? aB1 : aA1;
        const float pv1  = 1.0f / (lab1 ? sumB1 : sumA1);

        if (lane == 0) {
            out[(size_t)row0 * NEXP + 0] = pv0;
            out[(size_t)row0 * NEXP + 1] = (float)arg0;
            out[(size_t)(row0 + 1) * NEXP + 0] = pv1;
            out[(size_t)(row0 + 1) * NEXP + 1] = (float)arg1;
            atomicAdd(&denom[arg0], pv0);
            atomicAdd(&denom[arg1], pv1);
        }
    }
}

// Kernel B: finalize each row: out[row, e] = (e==top1) ? p/(denom+eps)*B : 0
__global__ __launch_bounds__(256) void finalize_kernel(
    float* __restrict__ out, const float* __restrict__ denom)
{
    const int row = blockIdx.x * blockDim.x + threadIdx.x;
    if (row >= NROWS) return;
    const float p = out[(size_t)row * NEXP + 0];
    const int   a = (int)out[(size_t)row * NEXP + 1];
    const float d = denom[a];
    const float val = p / (d + 1e-6f) * 65536.0f;

    float vals[NEXP];
#pragma unroll
    for (int e = 0; e < NEXP; ++e) vals[e] = (e == a) ? val : 0.0f;

    float4 o0 = make_float4(vals[0], vals[1], vals[2], vals[3]);
    float4 o1 = make_float4(vals[4], vals[5], vals[6], vals[7]);
    float4* dst = reinterpret_cast<float4*>(out + (size_t)row * NEXP);
    dst[0] = o0;
    dst[1] = o1;
}

extern "C" void kernel_launch(void* const* d_in, const int* in_sizes, int n_in,
                              void* d_out, int out_size, void* d_ws, size_t ws_size,
                              hipStream_t stream) {
    const float* x     = (const float*)d_in[0];
    const int*   label = (const int*)d_in[1];
    const float* w     = (const float*)d_in[2];
    const float* bg    = (const float*)d_in[3];
    float* out   = (float*)d_out;
    float* denom = (float*)d_ws;   // 8 floats

    hipMemsetAsync(denom, 0, NEXP * sizeof(float), stream);
    gate_kernel<<<NROWS / ROWS_PER_BLOCK, THREADS, 0, stream>>>(x, label, w, bg, out, denom);
    finalize_kernel<<<NROWS / 256, 256, 0, stream>>>(out, denom);
}

// Round 2
// 677.422 us; speedup vs baseline: 1.5377x; 1.5377x over previous
//
#include <hip/hip_runtime.h>
#include <hip/hip_bf16.h>

#define NROWS 65536
#define DDIM  2048
#define NEXP  8
#define THREADS 512
#define NBLOCKS 1024
#define ROWS_PER_BLOCK (NROWS / NBLOCKS)        // 64
#define ROWS_PER_WAVE  (ROWS_PER_BLOCK / 8)     // 8
#define QUADS          (ROWS_PER_WAVE / 4)      // 2
#define KSTEPS         (DDIM / 256)             // 8

// Kernel A: gate scores -> masked softmax -> top1 prob. Writes (p, top1) to
// out[row*8 + {0,1}]; accumulates denom via LDS then 8 global atomics/block.
__global__ __launch_bounds__(THREADS, 4) void gate_kernel(
    const float* __restrict__ x,       // (B, D)
    const int*   __restrict__ label,   // (B,)
    const float* __restrict__ w,       // (D, E) row-major
    const float* __restrict__ bgate,   // (E,)
    float* __restrict__ out,           // (B, E)
    float* __restrict__ denom)         // (E,) pre-zeroed
{
    __shared__ float wt[NEXP * DDIM];  // 64 KiB, wt[e*D + d]
    __shared__ float dsum[NEXP];

    const int tid = threadIdx.x;
    if (tid < NEXP) dsum[tid] = 0.0f;

    // Stage w transposed into LDS (coalesced float4 reads, 8 per thread).
    for (int i = tid; i < (DDIM * NEXP) / 4; i += THREADS) {
        float4 v = reinterpret_cast<const float4*>(w)[i];
        const int d0 = i >> 1;
        const int e0 = (i & 1) * 4;
        wt[(e0 + 0) * DDIM + d0] = v.x;
        wt[(e0 + 1) * DDIM + d0] = v.y;
        wt[(e0 + 2) * DDIM + d0] = v.z;
        wt[(e0 + 3) * DDIM + d0] = v.w;
    }
    float bg[NEXP];
#pragma unroll
    for (int e = 0; e < NEXP; ++e) bg[e] = bgate[e];
    __syncthreads();

    const int wave = tid >> 6;
    const int lane = tid & 63;
    const int wrow = blockIdx.x * ROWS_PER_BLOCK + wave * ROWS_PER_WAVE;
    const float* xb = x + (size_t)wrow * DDIM + lane * 4;

    // Software pipeline: cur holds this k-step's 4 row-chunks, nxt prefetches.
    float4 cur[4], nxt[4];
#pragma unroll
    for (int r = 0; r < 4; ++r)
        cur[r] = *reinterpret_cast<const float4*>(xb + r * DDIM);
#pragma unroll
    for (int r = 0; r < 4; ++r) nxt[r] = cur[r];   // silence uninit on last step

#pragma unroll
    for (int q = 0; q < QUADS; ++q) {
        float acc[4][NEXP];
#pragma unroll
        for (int r = 0; r < 4; ++r)
#pragma unroll
            for (int e = 0; e < NEXP; ++e) acc[r][e] = 0.0f;

#pragma unroll
        for (int k = 0; k < KSTEPS; ++k) {
            // Prefetch next step (or next quad's k=0) — compile-time branch.
            if (k < KSTEPS - 1) {
#pragma unroll
                for (int r = 0; r < 4; ++r)
                    nxt[r] = *reinterpret_cast<const float4*>(xb + (q * 4 + r) * DDIM + (k + 1) * 256);
            } else if (q < QUADS - 1) {
#pragma unroll
                for (int r = 0; r < 4; ++r)
                    nxt[r] = *reinterpret_cast<const float4*>(xb + ((q + 1) * 4 + r) * DDIM);
            }
#pragma unroll
            for (int e = 0; e < NEXP; ++e) {
                const float4 wv = *reinterpret_cast<const float4*>(&wt[e * DDIM + k * 256 + lane * 4]);
#pragma unroll
                for (int r = 0; r < 4; ++r)
                    acc[r][e] += cur[r].x * wv.x + cur[r].y * wv.y + cur[r].z * wv.z + cur[r].w * wv.w;
            }
#pragma unroll
            for (int r = 0; r < 4; ++r) cur[r] = nxt[r];
        }

        // Butterfly reduce each (row, expert) across 64 lanes.
#pragma unroll
        for (int r = 0; r < 4; ++r)
#pragma unroll
            for (int e = 0; e < NEXP; ++e)
#pragma unroll
                for (int m = 32; m >= 1; m >>= 1)
                    acc[r][e] += __shfl_xor(acc[r][e], m, 64);

        // Epilogue: all lanes compute identically; lane 0 writes.
#pragma unroll
        for (int r = 0; r < 4; ++r) {
            const int row = wrow + q * 4 + r;
            float s[NEXP];
#pragma unroll
            for (int e = 0; e < NEXP; ++e) s[e] = acc[r][e] + bg[e];

            float mA = s[0]; int aA = 0;
            if (s[1] > mA) { mA = s[1]; aA = 1; }
            if (s[2] > mA) { mA = s[2]; aA = 2; }
            if (s[3] > mA) { mA = s[3]; aA = 3; }
            const float sumA = __expf(s[0] - mA) + __expf(s[1] - mA) +
                               __expf(s[2] - mA) + __expf(s[3] - mA);
            float mB = s[4]; int aB = 4;
            if (s[5] > mB) { mB = s[5]; aB = 5; }
            if (s[6] > mB) { mB = s[6]; aB = 6; }
            if (s[7] > mB) { mB = s[7]; aB = 7; }
            const float sumB = __expf(s[4] - mB) + __expf(s[5] - mB) +
                               __expf(s[6] - mB) + __expf(s[7] - mB);

            const int   lab = label[row];
            const int   arg = lab ? aB : aA;
            const float pv  = 1.0f / (lab ? sumB : sumA);

            if (lane == 0) {
                out[(size_t)row * NEXP + 0] = pv;
                out[(size_t)row * NEXP + 1] = (float)arg;
                atomicAdd(&dsum[arg], pv);
            }
        }
    }

    __syncthreads();
    if (tid < NEXP) atomicAdd(&denom[tid], dsum[tid]);
}

// Kernel B: out[row, e] = (e==top1) ? p/(denom[e]+eps)*B : 0
__global__ __launch_bounds__(256) void finalize_kernel(
    float* __restrict__ out, const float* __restrict__ denom)
{
    const int row = blockIdx.x * blockDim.x + threadIdx.x;
    if (row >= NROWS) return;
    const float p = out[(size_t)row * NEXP + 0];
    const int   a = (int)out[(size_t)row * NEXP + 1];
    const float val = p / (denom[a] + 1e-6f) * 65536.0f;

    float vals[NEXP];
#pragma unroll
    for (int e = 0; e < NEXP; ++e) vals[e] = (e == a) ? val : 0.0f;

    float4* dst = reinterpret_cast<float4*>(out + (size_t)row * NEXP);
    dst[0] = make_float4(vals[0], vals[1], vals[2], vals[3]);
    dst[1] = make_float4(vals[4], vals[5], vals[6], vals[7]);
}

extern "C" void kernel_launch(void* const* d_in, const int* in_sizes, int n_in,
                              void* d_out, int out_size, void* d_ws, size_t ws_size,
                              hipStream_t stream) {
    const float* x     = (const float*)d_in[0];
    const int*   label = (const int*)d_in[1];
    const float* w     = (const float*)d_in[2];
    const float* bg    = (const float*)d_in[3];
    float* out   = (float*)d_out;
    float* denom = (float*)d_ws;   // 8 floats

    hipMemsetAsync(denom, 0, NEXP * sizeof(float), stream);
    gate_kernel<<<NBLOCKS, THREADS, 0, stream>>>(x, label, w, bg, out, denom);
    finalize_kernel<<<NROWS / 256, 256, 0, stream>>>(out, denom);
}